// Round 3
// baseline (261.335 us; speedup 1.0000x reference)
//
#include <hip/hip_runtime.h>
#include <hip/hip_bf16.h>

// AttentionHeadRankFour: B=8, X=8, S=1024, D_IN=512, D_OUT=64
// out = softmax_causal( (Xq Wq)(Xk Wk)^T / sqrt(S) ) (Xv Wv)
//
// Pass 0: wprep converts W (fp32) -> bf16 fragment-ordered (q_w pre-scaled 1/32).
// Pass 1: proj v3 — persistent waves, full-K per wave, register double-buffered
//         A-chunk pipeline (8 loads always in flight), W-frags in LDS.
// Pass 2: flash attention, bf16 MFMA, online softmax.

typedef short  short8 __attribute__((ext_vector_type(8)));
typedef float  f32x4  __attribute__((ext_vector_type(4)));

#define DIN   512
#define DOUT  64
#define SEQ   1024
#define NROWS 65536   // 8*8*1024

__device__ __forceinline__ unsigned short f2bf(float f) {
    unsigned int u = __float_as_uint(f);
    u += 0x7FFF + ((u >> 16) & 1);   // RNE
    return (unsigned short)(u >> 16);
}

// ---------------------------------------------------------------------------
// Weight prep: grid (16,3), 256 thr. Wfrag[mode][kk][nt][lane][8] bf16,
// element = W[kk*32 + lg*8 + j][nt*16 + lr]; mode 2 pre-scaled by 1/32.
// ---------------------------------------------------------------------------
__global__ __launch_bounds__(256)
void wprep_kernel(const float* __restrict__ k_w, const float* __restrict__ v_w,
                  const float* __restrict__ q_w, unsigned short* __restrict__ Wfrag)
{
    const int mode = blockIdx.y;
    const float* w = (mode == 0) ? k_w : (mode == 1) ? v_w : q_w;
    const float sc = (mode == 2) ? 0.03125f : 1.0f;
    unsigned short* outp = Wfrag + (size_t)mode * 32768;

    const int s  = blockIdx.x * 256 + threadIdx.x;   // (kk,nt,lane) slot
    const int l  = s & 63;
    const int nt = (s >> 6) & 3;
    const int kk = s >> 8;
    const int lr = l & 15, lg = l >> 4;
    short8 frag;
    #pragma unroll
    for (int j = 0; j < 8; ++j)
        frag[j] = (short)f2bf(w[(kk * 32 + lg * 8 + j) * 64 + nt * 16 + lr] * sc);
    *(short8*)&outp[(size_t)s * 8] = frag;
}

// ---------------------------------------------------------------------------
// proj v3. Grid (128, 3), 512 thr = 8 waves. Wave g = bx*8+wid owns 4 tiles
// (tile = g + it*1024) of 16 rows x full K=512. K in 4 chunks of 128 floats,
// register double-buffered: next chunk's 8 float4 loads issued before current
// chunk's MFMAs. W-fragments (64 KB) staged once to LDS.
// ---------------------------------------------------------------------------
__device__ __forceinline__ void issue_chunk(const float* __restrict__ p, float4 (&b)[8]) {
    #pragma unroll
    for (int k = 0; k < 4; ++k) {
        b[2 * k]     = *(const float4*)(p + k * 32);
        b[2 * k + 1] = *(const float4*)(p + k * 32 + 4);
    }
}

__device__ __forceinline__ void compute_chunk(const float4 (&b)[8], int c,
                                              const unsigned short* Wlds, int l,
                                              f32x4 (&acc)[4]) {
    #pragma unroll
    for (int k = 0; k < 4; ++k) {
        const int kk = c * 4 + k;
        short8 af;
        const float4 a0 = b[2 * k], a1 = b[2 * k + 1];
        af[0] = (short)f2bf(a0.x); af[1] = (short)f2bf(a0.y);
        af[2] = (short)f2bf(a0.z); af[3] = (short)f2bf(a0.w);
        af[4] = (short)f2bf(a1.x); af[5] = (short)f2bf(a1.y);
        af[6] = (short)f2bf(a1.z); af[7] = (short)f2bf(a1.w);
        #pragma unroll
        for (int nt = 0; nt < 4; ++nt) {
            const short8 bf = *(const short8*)&Wlds[(size_t)((kk * 4 + nt) * 64 + l) * 8];
            acc[nt] = __builtin_amdgcn_mfma_f32_16x16x32_bf16(af, bf, acc[nt], 0, 0, 0);
        }
    }
}

__global__ __launch_bounds__(512, 2)
void proj_kernel(const float* __restrict__ k_in, const float* __restrict__ v_in,
                 const float* __restrict__ q_in,
                 const unsigned short* __restrict__ Wfrag,
                 unsigned short* __restrict__ Kb, unsigned short* __restrict__ Vt,
                 unsigned short* __restrict__ Qb)
{
    const int mode = blockIdx.y;
    const float* in = (mode == 0) ? k_in : (mode == 1) ? v_in : q_in;
    const unsigned short* wf = Wfrag + (size_t)mode * 32768;

    __shared__ __align__(16) unsigned short Wlds[32768];   // 64 KB

    const int tid = threadIdx.x;
    #pragma unroll
    for (int i = 0; i < 8; ++i)
        *(short8*)&Wlds[(size_t)(i * 512 + tid) * 8] =
            *(const short8*)&wf[(size_t)(i * 512 + tid) * 8];
    __syncthreads();

    const int wid = tid >> 6;
    const int l   = tid & 63;
    const int lr  = l & 15;
    const int lg  = l >> 4;
    const int g   = blockIdx.x * 8 + wid;      // wave id in mode: 0..1023

    float4 bA[8], bB[8];
    // prologue: prefetch tile(it=0) chunk 0
    {
        const int tile0 = g;
        const float* base0 = in + (size_t)(tile0 * 16 + lr) * DIN + lg * 8;
        issue_chunk(base0, bA);
    }

    #pragma unroll 1
    for (int it = 0; it < 4; ++it) {
        const int tile  = g + it * 1024;
        const int ntile = (tile + 1024) & 4095;           // wraps: dummy but in-bounds
        const int r0    = tile * 16;
        const float* base  = in + (size_t)(r0 + lr) * DIN + lg * 8;
        const float* nbase = in + (size_t)(ntile * 16 + lr) * DIN + lg * 8;

        f32x4 acc[4];
        #pragma unroll
        for (int nt = 0; nt < 4; ++nt)
            #pragma unroll
            for (int i = 0; i < 4; ++i) acc[nt][i] = 0.f;

        issue_chunk(base + 128, bB);           // c1
        compute_chunk(bA, 0, Wlds, l, acc);
        issue_chunk(base + 256, bA);           // c2
        compute_chunk(bB, 1, Wlds, l, acc);
        issue_chunk(base + 384, bB);           // c3
        compute_chunk(bA, 2, Wlds, l, acc);
        issue_chunk(nbase, bA);                // next tile c0
        compute_chunk(bB, 3, Wlds, l, acc);

        // Epilogue. C frag: col = lr, row = lg*4 + i (rows within this 16-row tile).
        if (mode == 1) {
            const int grow = r0 + lg * 4;
            const int bx = grow >> 10, s = grow & 1023;
            #pragma unroll
            for (int nt = 0; nt < 4; ++nt) {
                ushort4 pk;
                pk.x = f2bf(acc[nt][0]); pk.y = f2bf(acc[nt][1]);
                pk.z = f2bf(acc[nt][2]); pk.w = f2bf(acc[nt][3]);
                *(ushort4*)&Vt[(size_t)bx * 65536 + (size_t)(nt * 16 + lr) * 1024 + s] = pk;
            }
        } else {
            unsigned short* outp = (mode == 0) ? Kb : Qb;
            #pragma unroll
            for (int nt = 0; nt < 4; ++nt)
                #pragma unroll
                for (int i = 0; i < 4; ++i)
                    outp[(size_t)(r0 + lg * 4 + i) * 64 + nt * 16 + lr] = f2bf(acc[nt][i]);
        }
    }
}

// ---------------------------------------------------------------------------
// Flash attention, causal. Grid: (16 q-blocks, 64 bx heads). 256 thr = 4 waves.
// Wave w owns q rows [qblk*64 + w*16, +16). KB=64 keys per chunk.
// ---------------------------------------------------------------------------
__global__ __launch_bounds__(256)
void attn_kernel(const unsigned short* __restrict__ Qb,
                 const unsigned short* __restrict__ Kb,
                 const unsigned short* __restrict__ Vt,
                 float* __restrict__ out)
{
    __shared__ __align__(16) unsigned short Plds[4][16][72];  // per-wave P tile, padded

    const int tid  = threadIdx.x;
    const int wid  = tid >> 6;
    const int l    = tid & 63;
    const int lr   = l & 15;
    const int lg   = l >> 4;
    const int qblk = 15 - (int)blockIdx.x;       // big blocks first
    const int bx   = blockIdx.y;
    const int qw0  = qblk * 64 + wid * 16;

    const unsigned short* Qp = Qb + (size_t)bx * 65536;
    const unsigned short* Kp = Kb + (size_t)bx * 65536;
    const unsigned short* Vp = Vt + (size_t)bx * 65536;   // [d][s]

    const short8 qa0 = *(const short8*)&Qp[(size_t)(qw0 + lr) * 64 + lg * 8];
    const short8 qa1 = *(const short8*)&Qp[(size_t)(qw0 + lr) * 64 + 32 + lg * 8];

    float m[4], lsum[4];
    f32x4 acc[4];
    #pragma unroll
    for (int i = 0; i < 4; ++i) { m[i] = -INFINITY; lsum[i] = 0.f; }
    #pragma unroll
    for (int dt = 0; dt < 4; ++dt)
        #pragma unroll
        for (int i = 0; i < 4; ++i) acc[dt][i] = 0.f;

    const int qrow = qw0 + lg * 4;   // + i

    for (int kb = 0; kb <= qw0; kb += 64) {
        // ---- scores: 4 tiles of 16 keys ----
        f32x4 s[4];
        #pragma unroll
        for (int kt = 0; kt < 4; ++kt) {
            const int kbase = kb + kt * 16;
            if (kbase <= qw0 + 15) {           // wave-uniform
                const short8 k0 = *(const short8*)&Kp[(size_t)(kbase + lr) * 64 + lg * 8];
                const short8 k1 = *(const short8*)&Kp[(size_t)(kbase + lr) * 64 + 32 + lg * 8];
                f32x4 t;
                #pragma unroll
                for (int i = 0; i < 4; ++i) t[i] = 0.f;
                t = __builtin_amdgcn_mfma_f32_16x16x32_bf16(qa0, k0, t, 0, 0, 0);
                t = __builtin_amdgcn_mfma_f32_16x16x32_bf16(qa1, k1, t, 0, 0, 0);
                const int kcol = kbase + lr;
                #pragma unroll
                for (int i = 0; i < 4; ++i)
                    s[kt][i] = (kcol <= qrow + i) ? t[i] : -INFINITY;
            } else {
                #pragma unroll
                for (int i = 0; i < 4; ++i) s[kt][i] = -INFINITY;
            }
        }
        // ---- online softmax ----
        float tm[4];
        #pragma unroll
        for (int i = 0; i < 4; ++i)
            tm[i] = fmaxf(fmaxf(s[0][i], s[1][i]), fmaxf(s[2][i], s[3][i]));
        #pragma unroll
        for (int d = 1; d < 16; d <<= 1)
            #pragma unroll
            for (int i = 0; i < 4; ++i)
                tm[i] = fmaxf(tm[i], __shfl_xor(tm[i], d));

        float rs[4], ps[4];
        #pragma unroll
        for (int i = 0; i < 4; ++i) {
            const float mn = fmaxf(m[i], tm[i]);
            rs[i] = __expf(m[i] - mn);
            m[i] = mn;
            ps[i] = 0.f;
        }
        #pragma unroll
        for (int kt = 0; kt < 4; ++kt)
            #pragma unroll
            for (int i = 0; i < 4; ++i) {
                const float p = __expf(s[kt][i] - m[i]);   // masked -> 0
                ps[i] += p;
                Plds[wid][lg * 4 + i][kt * 16 + lr] = f2bf(p);
            }
        #pragma unroll
        for (int d = 1; d < 16; d <<= 1)
            #pragma unroll
            for (int i = 0; i < 4; ++i) ps[i] += __shfl_xor(ps[i], d);
        #pragma unroll
        for (int i = 0; i < 4; ++i) lsum[i] = lsum[i] * rs[i] + ps[i];
        #pragma unroll
        for (int dt = 0; dt < 4; ++dt)
            #pragma unroll
            for (int i = 0; i < 4; ++i) acc[dt][i] *= rs[i];

        // wave-private LDS write -> read (same wave); drain LDS then re-read
        asm volatile("s_waitcnt lgkmcnt(0)" ::: "memory");
        __builtin_amdgcn_sched_barrier(0);

        // ---- PV ----
        const int cmax = (kb + 32 <= qw0 + 15) ? 2 : 1;
        for (int c = 0; c < cmax; ++c) {
            const short8 pa = *(const short8*)&Plds[wid][lr][c * 32 + lg * 8];
            #pragma unroll
            for (int dt = 0; dt < 4; ++dt) {
                const short8 vb = *(const short8*)&Vp[(size_t)(dt * 16 + lr) * 1024 + kb + c * 32 + lg * 8];
                acc[dt] = __builtin_amdgcn_mfma_f32_16x16x32_bf16(pa, vb, acc[dt], 0, 0, 0);
            }
        }
        asm volatile("s_waitcnt lgkmcnt(0)" ::: "memory");
    }

    // ---- epilogue ----
    float inv[4];
    #pragma unroll
    for (int i = 0; i < 4; ++i) inv[i] = 1.0f / lsum[i];
    const size_t orow = (size_t)bx * 1024 + qw0;
    #pragma unroll
    for (int dt = 0; dt < 4; ++dt)
        #pragma unroll
        for (int i = 0; i < 4; ++i)
            out[(orow + lg * 4 + i) * 64 + dt * 16 + lr] = acc[dt][i] * inv[i];
}

extern "C" void kernel_launch(void* const* d_in, const int* in_sizes, int n_in,
                              void* d_out, int out_size, void* d_ws, size_t ws_size,
                              hipStream_t stream) {
    const float* k_in = (const float*)d_in[0];
    const float* v_in = (const float*)d_in[1];
    const float* q_in = (const float*)d_in[2];
    const float* k_w  = (const float*)d_in[3];
    const float* v_w  = (const float*)d_in[4];
    const float* q_w  = (const float*)d_in[5];

    unsigned short* Kb    = (unsigned short*)d_ws;              // [65536][64] bf16
    unsigned short* Vt    = Kb + (size_t)NROWS * 64;            // [64][64][1024] bf16
    unsigned short* Qb    = Vt + (size_t)NROWS * 64;            // [65536][64] bf16 (scale in W)
    unsigned short* Wfrag = Qb + (size_t)NROWS * 64;            // 3 x 32768 bf16 fragments

    wprep_kernel<<<dim3(16, 3), 256, 0, stream>>>(k_w, v_w, q_w, Wfrag);
    proj_kernel<<<dim3(128, 3), 512, 0, stream>>>(
        k_in, v_in, q_in, Wfrag, Kb, Vt, Qb);
    attn_kernel<<<dim3(16, 64), 256, 0, stream>>>(Qb, Kb, Vt, (float*)d_out);
}

// Round 4
// 201.819 us; speedup vs baseline: 1.2949x; 1.2949x over previous
//
#include <hip/hip_runtime.h>
#include <hip/hip_bf16.h>

// AttentionHeadRankFour: B=8, X=8, S=1024, D_IN=512, D_OUT=64
// out = softmax_causal( (Xq Wq)(Xk Wk)^T / sqrt(S) ) (Xv Wv)
//
// Pass 0: wprep converts W (fp32) -> bf16 fragment-ordered (q_w pre-scaled 1/32).
// Pass 1: proj v4 — 16-wave blocks, 1 tile/wave, W in LDS, register
//         double-buffered A-chunks (8 x 1KB in flight per wave), grid 768.
// Pass 2: flash attention, bf16 MFMA, online softmax.

typedef short  short8 __attribute__((ext_vector_type(8)));
typedef float  f32x4  __attribute__((ext_vector_type(4)));

#define DIN   512
#define DOUT  64
#define SEQ   1024
#define NROWS 65536   // 8*8*1024

__device__ __forceinline__ unsigned short f2bf(float f) {
    unsigned int u = __float_as_uint(f);
    u += 0x7FFF + ((u >> 16) & 1);   // RNE
    return (unsigned short)(u >> 16);
}

// ---------------------------------------------------------------------------
// Weight prep: grid (16,3), 256 thr. Wfrag[mode][kk][nt][lane][8] bf16,
// element = W[kk*32 + lg*8 + j][nt*16 + lr]; mode 2 pre-scaled by 1/32.
// ---------------------------------------------------------------------------
__global__ __launch_bounds__(256)
void wprep_kernel(const float* __restrict__ k_w, const float* __restrict__ v_w,
                  const float* __restrict__ q_w, unsigned short* __restrict__ Wfrag)
{
    const int mode = blockIdx.y;
    const float* w = (mode == 0) ? k_w : (mode == 1) ? v_w : q_w;
    const float sc = (mode == 2) ? 0.03125f : 1.0f;
    unsigned short* outp = Wfrag + (size_t)mode * 32768;

    const int s  = blockIdx.x * 256 + threadIdx.x;   // (kk,nt,lane) slot
    const int l  = s & 63;
    const int nt = (s >> 6) & 3;
    const int kk = s >> 8;
    const int lr = l & 15, lg = l >> 4;
    short8 frag;
    #pragma unroll
    for (int j = 0; j < 8; ++j)
        frag[j] = (short)f2bf(w[(kk * 32 + lg * 8 + j) * 64 + nt * 16 + lr] * sc);
    *(short8*)&outp[(size_t)s * 8] = frag;
}

// ---------------------------------------------------------------------------
// proj v4. Grid (256, 3), 1024 thr = 16 waves, __launch_bounds__(1024,4).
// Wave w owns tile = bx*16 + w: 16 rows x full K=512, K in 4 chunks of 128,
// register double-buffered. W-fragments (64 KB) staged once to LDS.
// mode 0: keys -> Kb [row][64]; 1: values -> Vt [bx][d][s]; 2: queries -> Qb.
// ---------------------------------------------------------------------------
__device__ __forceinline__ void issue_chunk(const float* __restrict__ p, float4 (&b)[8]) {
    #pragma unroll
    for (int k = 0; k < 4; ++k) {
        b[2 * k]     = *(const float4*)(p + k * 32);
        b[2 * k + 1] = *(const float4*)(p + k * 32 + 4);
    }
}

__device__ __forceinline__ void compute_chunk(const float4 (&b)[8], int c,
                                              const unsigned short* Wlds, int l,
                                              f32x4 (&acc)[4]) {
    #pragma unroll
    for (int k = 0; k < 4; ++k) {
        const int kk = c * 4 + k;
        short8 af;
        const float4 a0 = b[2 * k], a1 = b[2 * k + 1];
        af[0] = (short)f2bf(a0.x); af[1] = (short)f2bf(a0.y);
        af[2] = (short)f2bf(a0.z); af[3] = (short)f2bf(a0.w);
        af[4] = (short)f2bf(a1.x); af[5] = (short)f2bf(a1.y);
        af[6] = (short)f2bf(a1.z); af[7] = (short)f2bf(a1.w);
        #pragma unroll
        for (int nt = 0; nt < 4; ++nt) {
            const short8 bf = *(const short8*)&Wlds[(size_t)((kk * 4 + nt) * 64 + l) * 8];
            acc[nt] = __builtin_amdgcn_mfma_f32_16x16x32_bf16(af, bf, acc[nt], 0, 0, 0);
        }
    }
}

__global__ __launch_bounds__(1024, 4)
void proj_kernel(const float* __restrict__ k_in, const float* __restrict__ v_in,
                 const float* __restrict__ q_in,
                 const unsigned short* __restrict__ Wfrag,
                 unsigned short* __restrict__ Kb, unsigned short* __restrict__ Vt,
                 unsigned short* __restrict__ Qb)
{
    const int mode = blockIdx.y;
    const float* in = (mode == 0) ? k_in : (mode == 1) ? v_in : q_in;
    const unsigned short* wf = Wfrag + (size_t)mode * 32768;

    __shared__ __align__(16) unsigned short Wlds[32768];   // 64 KB

    const int tid = threadIdx.x;
    const int wid = tid >> 6;
    const int l   = tid & 63;
    const int lr  = l & 15;
    const int lg  = l >> 4;
    const int tile = blockIdx.x * 16 + wid;     // 0..4095
    const int r0   = tile * 16;

    const float* base = in + (size_t)(r0 + lr) * DIN + lg * 8;

    // Chunk-0 A-loads first: their HBM latency hides under the W-stage+barrier.
    float4 bA[8], bB[8];
    issue_chunk(base, bA);

    // Stage W fragments: 64 KB, 1024 threads -> 4 x 16B each.
    #pragma unroll
    for (int i = 0; i < 4; ++i)
        *(short8*)&Wlds[(size_t)(i * 1024 + tid) * 8] =
            *(const short8*)&wf[(size_t)(i * 1024 + tid) * 8];
    __syncthreads();

    f32x4 acc[4];
    #pragma unroll
    for (int nt = 0; nt < 4; ++nt)
        #pragma unroll
        for (int i = 0; i < 4; ++i) acc[nt][i] = 0.f;

    issue_chunk(base + 128, bB);           // c1
    compute_chunk(bA, 0, Wlds, l, acc);
    issue_chunk(base + 256, bA);           // c2
    compute_chunk(bB, 1, Wlds, l, acc);
    issue_chunk(base + 384, bB);           // c3
    compute_chunk(bA, 2, Wlds, l, acc);
    compute_chunk(bB, 3, Wlds, l, acc);

    // Epilogue. C frag: col = lr, row = lg*4 + i (rows within this 16-row tile).
    if (mode == 1) {
        const int grow = r0 + lg * 4;
        const int bx = grow >> 10, s = grow & 1023;
        #pragma unroll
        for (int nt = 0; nt < 4; ++nt) {
            ushort4 pk;
            pk.x = f2bf(acc[nt][0]); pk.y = f2bf(acc[nt][1]);
            pk.z = f2bf(acc[nt][2]); pk.w = f2bf(acc[nt][3]);
            *(ushort4*)&Vt[(size_t)bx * 65536 + (size_t)(nt * 16 + lr) * 1024 + s] = pk;
        }
    } else {
        unsigned short* outp = (mode == 0) ? Kb : Qb;
        #pragma unroll
        for (int nt = 0; nt < 4; ++nt)
            #pragma unroll
            for (int i = 0; i < 4; ++i)
                outp[(size_t)(r0 + lg * 4 + i) * 64 + nt * 16 + lr] = f2bf(acc[nt][i]);
    }
}

// ---------------------------------------------------------------------------
// Flash attention, causal. Grid: (16 q-blocks, 64 bx heads). 256 thr = 4 waves.
// Wave w owns q rows [qblk*64 + w*16, +16). KB=64 keys per chunk.
// ---------------------------------------------------------------------------
__global__ __launch_bounds__(256)
void attn_kernel(const unsigned short* __restrict__ Qb,
                 const unsigned short* __restrict__ Kb,
                 const unsigned short* __restrict__ Vt,
                 float* __restrict__ out)
{
    __shared__ __align__(16) unsigned short Plds[4][16][72];  // per-wave P tile, padded

    const int tid  = threadIdx.x;
    const int wid  = tid >> 6;
    const int l    = tid & 63;
    const int lr   = l & 15;
    const int lg   = l >> 4;
    const int qblk = 15 - (int)blockIdx.x;       // big blocks first
    const int bx   = blockIdx.y;
    const int qw0  = qblk * 64 + wid * 16;

    const unsigned short* Qp = Qb + (size_t)bx * 65536;
    const unsigned short* Kp = Kb + (size_t)bx * 65536;
    const unsigned short* Vp = Vt + (size_t)bx * 65536;   // [d][s]

    const short8 qa0 = *(const short8*)&Qp[(size_t)(qw0 + lr) * 64 + lg * 8];
    const short8 qa1 = *(const short8*)&Qp[(size_t)(qw0 + lr) * 64 + 32 + lg * 8];

    float m[4], lsum[4];
    f32x4 acc[4];
    #pragma unroll
    for (int i = 0; i < 4; ++i) { m[i] = -INFINITY; lsum[i] = 0.f; }
    #pragma unroll
    for (int dt = 0; dt < 4; ++dt)
        #pragma unroll
        for (int i = 0; i < 4; ++i) acc[dt][i] = 0.f;

    const int qrow = qw0 + lg * 4;   // + i

    for (int kb = 0; kb <= qw0; kb += 64) {
        // ---- scores: 4 tiles of 16 keys ----
        f32x4 s[4];
        #pragma unroll
        for (int kt = 0; kt < 4; ++kt) {
            const int kbase = kb + kt * 16;
            if (kbase <= qw0 + 15) {           // wave-uniform
                const short8 k0 = *(const short8*)&Kp[(size_t)(kbase + lr) * 64 + lg * 8];
                const short8 k1 = *(const short8*)&Kp[(size_t)(kbase + lr) * 64 + 32 + lg * 8];
                f32x4 t;
                #pragma unroll
                for (int i = 0; i < 4; ++i) t[i] = 0.f;
                t = __builtin_amdgcn_mfma_f32_16x16x32_bf16(qa0, k0, t, 0, 0, 0);
                t = __builtin_amdgcn_mfma_f32_16x16x32_bf16(qa1, k1, t, 0, 0, 0);
                const int kcol = kbase + lr;
                #pragma unroll
                for (int i = 0; i < 4; ++i)
                    s[kt][i] = (kcol <= qrow + i) ? t[i] : -INFINITY;
            } else {
                #pragma unroll
                for (int i = 0; i < 4; ++i) s[kt][i] = -INFINITY;
            }
        }
        // ---- online softmax ----
        float tm[4];
        #pragma unroll
        for (int i = 0; i < 4; ++i)
            tm[i] = fmaxf(fmaxf(s[0][i], s[1][i]), fmaxf(s[2][i], s[3][i]));
        #pragma unroll
        for (int d = 1; d < 16; d <<= 1)
            #pragma unroll
            for (int i = 0; i < 4; ++i)
                tm[i] = fmaxf(tm[i], __shfl_xor(tm[i], d));

        float rs[4], ps[4];
        #pragma unroll
        for (int i = 0; i < 4; ++i) {
            const float mn = fmaxf(m[i], tm[i]);
            rs[i] = __expf(m[i] - mn);
            m[i] = mn;
            ps[i] = 0.f;
        }
        #pragma unroll
        for (int kt = 0; kt < 4; ++kt)
            #pragma unroll
            for (int i = 0; i < 4; ++i) {
                const float p = __expf(s[kt][i] - m[i]);   // masked -> 0
                ps[i] += p;
                Plds[wid][lg * 4 + i][kt * 16 + lr] = f2bf(p);
            }
        #pragma unroll
        for (int d = 1; d < 16; d <<= 1)
            #pragma unroll
            for (int i = 0; i < 4; ++i) ps[i] += __shfl_xor(ps[i], d);
        #pragma unroll
        for (int i = 0; i < 4; ++i) lsum[i] = lsum[i] * rs[i] + ps[i];
        #pragma unroll
        for (int dt = 0; dt < 4; ++dt)
            #pragma unroll
            for (int i = 0; i < 4; ++i) acc[dt][i] *= rs[i];

        // wave-private LDS write -> read (same wave); drain LDS then re-read
        asm volatile("s_waitcnt lgkmcnt(0)" ::: "memory");
        __builtin_amdgcn_sched_barrier(0);

        // ---- PV ----
        const int cmax = (kb + 32 <= qw0 + 15) ? 2 : 1;
        for (int c = 0; c < cmax; ++c) {
            const short8 pa = *(const short8*)&Plds[wid][lr][c * 32 + lg * 8];
            #pragma unroll
            for (int dt = 0; dt < 4; ++dt) {
                const short8 vb = *(const short8*)&Vp[(size_t)(dt * 16 + lr) * 1024 + kb + c * 32 + lg * 8];
                acc[dt] = __builtin_amdgcn_mfma_f32_16x16x32_bf16(pa, vb, acc[dt], 0, 0, 0);
            }
        }
        asm volatile("s_waitcnt lgkmcnt(0)" ::: "memory");
    }

    // ---- epilogue ----
    float inv[4];
    #pragma unroll
    for (int i = 0; i < 4; ++i) inv[i] = 1.0f / lsum[i];
    const size_t orow = (size_t)bx * 1024 + qw0;
    #pragma unroll
    for (int dt = 0; dt < 4; ++dt)
        #pragma unroll
        for (int i = 0; i < 4; ++i)
            out[(orow + lg * 4 + i) * 64 + dt * 16 + lr] = acc[dt][i] * inv[i];
}

extern "C" void kernel_launch(void* const* d_in, const int* in_sizes, int n_in,
                              void* d_out, int out_size, void* d_ws, size_t ws_size,
                              hipStream_t stream) {
    const float* k_in = (const float*)d_in[0];
    const float* v_in = (const float*)d_in[1];
    const float* q_in = (const float*)d_in[2];
    const float* k_w  = (const float*)d_in[3];
    const float* v_w  = (const float*)d_in[4];
    const float* q_w  = (const float*)d_in[5];

    unsigned short* Kb    = (unsigned short*)d_ws;              // [65536][64] bf16
    unsigned short* Vt    = Kb + (size_t)NROWS * 64;            // [64][64][1024] bf16
    unsigned short* Qb    = Vt + (size_t)NROWS * 64;            // [65536][64] bf16 (scale in W)
    unsigned short* Wfrag = Qb + (size_t)NROWS * 64;            // 3 x 32768 bf16 fragments

    wprep_kernel<<<dim3(16, 3), 256, 0, stream>>>(k_w, v_w, q_w, Wfrag);
    proj_kernel<<<dim3(256, 3), 1024, 0, stream>>>(
        k_in, v_in, q_in, Wfrag, Kb, Vt, Qb);
    attn_kernel<<<dim3(16, 64), 256, 0, stream>>>(Qb, Kb, Vt, (float*)d_out);
}